// Round 1
// baseline (361.567 us; speedup 1.0000x reference)
//
#include <hip/hip_runtime.h>
#include <math.h>

// WaveletKANClassifier, MI355X gfx950. fp32 I/O, bf16 MFMA compute.
//
// Round-4: evict the divergent haar fp64 boundary recheck from the hot
// kernel. Theory: ~200 Poisson-scattered triggers each cost a 768-iter
// fp64 gather loop (~20-40k cyc, 1 active lane) and stall the whole block
// at the next barrier -> straggler tail (Occupancy 19.7%, all pipes <20%).
//  K1 now: on dmin<2e-4, atomicAdd-append row to a worklist in d_ws and
//          use the cheap fp32 classification provisionally.
//  K2 fix_kernel: fixed 256-block grid (graph-static), recomputes the full
//          output row (fp32 direct/wavelet/LN, fp64 haar classification)
//          for each flagged row. Strictly more accurate than the old path.

#define B_SZ  32768
#define DIN   768
#define DOUT  768
#define NWAV  48

// d_ws fragment-major layout (units: shorts). Fragment tile = 64 lanes x 8
// bf16 = 512 shorts; lane L holds M[c0+(L&31)][k0 + (L>>5)*8 + j].
#define WF_OFF   0        // W:  24 cb x 48 kb tiles = 589824
#define WPH_OFF  589824   // Wp hi: 2 ct x 48 kb = 49152
#define WPL_OFF  638976   // Wp lo: 49152
#define WCF_OFF  688128   // Wc: 24 cb x 3 kb = 36864
#define WL_OFF   724992   // worklist: u32 count + u32 rows[WL_CAP-1]
#define WL_CAP   8192     // 32 KiB + 4 B; expected ~200 entries

typedef short bf16x8 __attribute__((ext_vector_type(8)));
typedef float f32x16 __attribute__((ext_vector_type(16)));

__device__ __forceinline__ float bf2f(short u) {
    union { unsigned int i; float f; } v;
    v.i = ((unsigned int)(unsigned short)u) << 16;
    return v.f;
}
__device__ __forceinline__ short f2bf(float f) {
    union { float f; unsigned int i; } v; v.f = f;
    unsigned int r = v.i + 0x7FFFu + ((v.i >> 16) & 1u);  // RNE
    return (short)(r >> 16);
}

// ---------------------------------------------------------------- K0: pack
// 1320 fragment tiles: [0,1152) W, [1152,1248) Wp hi+lo, [1248,1320) Wc.
__global__ __launch_bounds__(256) void pack_kernel(
    const float* __restrict__ W, const float* __restrict__ Wp,
    const float* __restrict__ Wc, short* __restrict__ ws)
{
    if (blockIdx.x == 0 && threadIdx.x == 0)
        *reinterpret_cast<unsigned*>(ws + WL_OFF) = 0u;  // reset worklist

    const int gw = (blockIdx.x * 256 + threadIdx.x) >> 6;
    const int L  = threadIdx.x & 63;
    const int lm = L & 31, half = L >> 5;

    if (gw < 1152) {                       // W [768 x 768]
        const int cb = gw / 48, kb = gw % 48;
        const int row = cb * 32 + lm;
        const int k = kb * 16 + half * 8;
        bf16x8 o;
#pragma unroll
        for (int j = 0; j < 8; j++) o[j] = f2bf(W[(size_t)row * DIN + k + j]);
        *reinterpret_cast<bf16x8*>(&ws[WF_OFF + (size_t)gw * 512 + L * 8]) = o;
    } else if (gw < 1248) {                // Wp [48 x 768], hi/lo, pad rows->64
        const int t = gw - 1152;
        const int ct = t / 48, kb = t % 48;
        const int j = ct * 32 + lm;
        const int k = kb * 16 + half * 8;
        bf16x8 h, l;
#pragma unroll
        for (int jj = 0; jj < 8; jj++) {
            float v = (j < NWAV) ? Wp[(size_t)j * DIN + k + jj] : 0.f;
            const short hh = f2bf(v);
            h[jj] = hh;
            l[jj] = f2bf(v - bf2f(hh));
        }
        *reinterpret_cast<bf16x8*>(&ws[WPH_OFF + (size_t)t * 512 + L * 8]) = h;
        *reinterpret_cast<bf16x8*>(&ws[WPL_OFF + (size_t)t * 512 + L * 8]) = l;
    } else if (gw < 1320) {                // Wc [768 x 48]
        const int t = gw - 1248;
        const int cb = t / 3, kb = t % 3;
        const int row = cb * 32 + lm;
        const int k = kb * 16 + half * 8;
        bf16x8 o;
#pragma unroll
        for (int jj = 0; jj < 8; jj++) o[jj] = f2bf(Wc[(size_t)row * NWAV + k + jj]);
        *reinterpret_cast<bf16x8*>(&ws[WCF_OFF + (size_t)t * 512 + L * 8]) = o;
    }
}

// ---------------------------------------------------------------- K1: fused
__global__ __launch_bounds__(512, 2) void fused_kernel(
    const float* __restrict__ x, const short* __restrict__ ws,
    unsigned* __restrict__ wl,
    const float* __restrict__ bp, const float* __restrict__ sc,
    const float* __restrict__ tr,
    const float* __restrict__ bb, const float* __restrict__ bc,
    const float* __restrict__ gm, const float* __restrict__ bt,
    float* __restrict__ out)
{
    // x tiles: 64 rows x 64 k bf16, row stride 72 shorts (144 B = 9 granules,
    // 9 coprime 8 -> conflict-free b128 frag reads). Double-buffered hi + lo.
    __shared__ __align__(16) short xh[2][64 * 72];
    __shared__ __align__(16) short xl[2][64 * 72];
    __shared__ float redS[64 * 8], redQ[64 * 8];
    __shared__ float muA[64], rsA[64];

    const short* WF  = ws + WF_OFF;
    const short* WPH = ws + WPH_OFF;
    const short* WPL = ws + WPL_OFF;
    const short* WCF = ws + WCF_OFF;

    const int tid = threadIdx.x;
    const int r0  = blockIdx.x * 64;
    const int wv  = tid >> 6, L = tid & 63;
    const int lm  = L & 31, half = L >> 5;

    f32x16 acc[2][3];                 // [rt (row 32-block)][ct (col 32-block)]
#pragma unroll
    for (int rt = 0; rt < 2; rt++)
#pragma unroll
        for (int ct = 0; ct < 3; ct++)
#pragma unroll
            for (int g = 0; g < 16; g++) acc[rt][ct][g] = 0.f;
    f32x16 wacc;                      // wi acc (waves 0-3)
#pragma unroll
    for (int g = 0; g < 16; g++) wacc[g] = 0.f;

    const int wrt = wv & 1, wct = wv >> 1;     // wi tile for wv<4

    // staging role: thread -> (row, 8-k chunk)
    const int srow = tid >> 3;
    const int sk   = (tid & 7) * 8;

    // ---- prologue: stage k0=0 into buf 0
    {
        const float4* xp = reinterpret_cast<const float4*>(&x[(size_t)(r0 + srow) * DIN + sk]);
        const float4 v0 = xp[0], v1 = xp[1];
        const float f[8] = {v0.x, v0.y, v0.z, v0.w, v1.x, v1.y, v1.z, v1.w};
        bf16x8 hh, ll;
#pragma unroll
        for (int i = 0; i < 8; i++) {
            const short h = f2bf(f[i]);
            hh[i] = h;
            ll[i] = f2bf(f[i] - bf2f(h));
        }
        *reinterpret_cast<bf16x8*>(&xh[0][srow * 72 + sk]) = hh;
        *reinterpret_cast<bf16x8*>(&xl[0][srow * 72 + sk]) = ll;
    }
    __syncthreads();

    // ---- K loop: 12 chunks of 64
    for (int k0i = 0; k0i < 12; ++k0i) {
        const int cur = k0i & 1;
        float4 v0, v1;
        if (k0i < 11) {  // prefetch next x chunk (completes under compute)
            const float4* xp = reinterpret_cast<const float4*>(
                &x[(size_t)(r0 + srow) * DIN + (k0i + 1) * 64 + sk]);
            v0 = xp[0]; v1 = xp[1];
        }
        const int kb0 = k0i * 4;

        // direct path: 2 rt x 3 ct x 4 ksteps
#pragma unroll
        for (int ks = 0; ks < 4; ++ks) {
            const bf16x8 a0 = *reinterpret_cast<bf16x8*>(&xh[cur][lm * 72 + ks * 16 + half * 8]);
            const bf16x8 a1 = *reinterpret_cast<bf16x8*>(&xh[cur][(32 + lm) * 72 + ks * 16 + half * 8]);
#pragma unroll
            for (int ct = 0; ct < 3; ++ct) {
                const bf16x8 b = *reinterpret_cast<const bf16x8*>(
                    &WF[((size_t)((wv * 3 + ct) * 48 + kb0 + ks)) * 512 + L * 8]);
                acc[0][ct] = __builtin_amdgcn_mfma_f32_32x32x16_bf16(a0, b, acc[0][ct], 0, 0, 0);
                acc[1][ct] = __builtin_amdgcn_mfma_f32_32x32x16_bf16(a1, b, acc[1][ct], 0, 0, 0);
            }
        }

        // wi path (waves 0-3): split-bf16, 3 MFMA per kstep
        if (wv < 4) {
#pragma unroll
            for (int ks = 0; ks < 4; ++ks) {
                const bf16x8 ah = *reinterpret_cast<bf16x8*>(&xh[cur][(wrt * 32 + lm) * 72 + ks * 16 + half * 8]);
                const bf16x8 al = *reinterpret_cast<bf16x8*>(&xl[cur][(wrt * 32 + lm) * 72 + ks * 16 + half * 8]);
                const bf16x8 bh = *reinterpret_cast<const bf16x8*>(
                    &WPH[((size_t)(wct * 48 + kb0 + ks)) * 512 + L * 8]);
                const bf16x8 bl = *reinterpret_cast<const bf16x8*>(
                    &WPL[((size_t)(wct * 48 + kb0 + ks)) * 512 + L * 8]);
                wacc = __builtin_amdgcn_mfma_f32_32x32x16_bf16(ah, bl, wacc, 0, 0, 0);
                wacc = __builtin_amdgcn_mfma_f32_32x32x16_bf16(al, bh, wacc, 0, 0, 0);
                wacc = __builtin_amdgcn_mfma_f32_32x32x16_bf16(ah, bh, wacc, 0, 0, 0);
            }
        }

        // stage next chunk into 1-cur (other waves only read cur this iter)
        if (k0i < 11) {
            const float f[8] = {v0.x, v0.y, v0.z, v0.w, v1.x, v1.y, v1.z, v1.w};
            bf16x8 hh, ll;
#pragma unroll
            for (int i = 0; i < 8; i++) {
                const short h = f2bf(f[i]);
                hh[i] = h;
                ll[i] = f2bf(f[i] - bf2f(h));
            }
            *reinterpret_cast<bf16x8*>(&xh[1 - cur][srow * 72 + sk]) = hh;
            *reinterpret_cast<bf16x8*>(&xl[1 - cur][srow * 72 + sk]) = ll;
        }
        __syncthreads();
    }

    // ---- wavelet activation + GELU -> wav tile in LDS (reuse xh[0])
    short* wavL = &xh[0][0];
    if (wv < 4) {
        const int j = wct * 32 + lm;
        if (j < NWAV) {
            const float bpv = bp[j], scv = sc[j], trv = tr[j];
#pragma unroll
            for (int g = 0; g < 16; ++g) {
                const int rowl = wrt * 32 + (g & 3) + 8 * (g >> 2) + 4 * half;  // C/D map
                const float wi = wacc[g] + bpv;
                const float s = (wi - trv) / scv;
                float w;
                if (j < 16) {
                    // haar: flag boundary band rows for the fix_kernel pass;
                    // classify provisionally in fp32 (row gets fully redone).
                    const float dmin = fminf(fabsf(s), fminf(fabsf(s - 0.5f), fabsf(s - 1.0f)));
                    if (dmin < 2e-4f) {
                        const unsigned idx = atomicAdd(&wl[0], 1u);
                        if (idx < WL_CAP - 1) wl[1 + idx] = (unsigned)(r0 + rowl);
                    }
                    w = (s >= 0.f && s < 0.5f) ? 1.f : ((s >= 0.5f && s < 1.f) ? -1.f : 0.f);
                } else if (j < 32) {
                    w = (1.f - s * s) * expf(-0.5f * s * s);
                } else {
                    w = cosf(5.f * s) * expf(-0.5f * s * s);
                }
                const float gel = 0.5f * w * (1.f + erff(w * 0.70710678118654752f));
                wavL[rowl * 72 + j] = f2bf(gel);
            }
        }
    }
    __syncthreads();

    // ---- h += wav @ Wc^T  (K=48 -> 3 ksteps)
#pragma unroll
    for (int ks = 0; ks < 3; ++ks) {
        const bf16x8 a0 = *reinterpret_cast<bf16x8*>(&wavL[lm * 72 + ks * 16 + half * 8]);
        const bf16x8 a1 = *reinterpret_cast<bf16x8*>(&wavL[(32 + lm) * 72 + ks * 16 + half * 8]);
#pragma unroll
        for (int ct = 0; ct < 3; ++ct) {
            const bf16x8 b = *reinterpret_cast<const bf16x8*>(
                &WCF[((size_t)((wv * 3 + ct) * 3 + ks)) * 512 + L * 8]);
            acc[0][ct] = __builtin_amdgcn_mfma_f32_32x32x16_bf16(a0, b, acc[0][ct], 0, 0, 0);
            acc[1][ct] = __builtin_amdgcn_mfma_f32_32x32x16_bf16(a1, b, acc[1][ct], 0, 0, 0);
        }
    }

    // ---- bias + LN reduction
    float bias[3], gmv[3], btv[3];
#pragma unroll
    for (int ct = 0; ct < 3; ++ct) {
        const int col = wv * 96 + ct * 32 + lm;
        bias[ct] = bb[col] + bc[col];
        gmv[ct] = gm[col];
        btv[ct] = bt[col];
    }
#pragma unroll
    for (int rt = 0; rt < 2; ++rt) {
#pragma unroll
        for (int g = 0; g < 16; ++g) {
            const float v0 = acc[rt][0][g] + bias[0];
            const float v1 = acc[rt][1][g] + bias[1];
            const float v2 = acc[rt][2][g] + bias[2];
            acc[rt][0][g] = v0; acc[rt][1][g] = v1; acc[rt][2][g] = v2;
            float s1 = v0 + v1 + v2;
            float s2 = v0 * v0 + v1 * v1 + v2 * v2;
            // reduce across the 32 lanes of this half (same output row)
            s1 += __shfl_xor(s1, 1);  s2 += __shfl_xor(s2, 1);
            s1 += __shfl_xor(s1, 2);  s2 += __shfl_xor(s2, 2);
            s1 += __shfl_xor(s1, 4);  s2 += __shfl_xor(s2, 4);
            s1 += __shfl_xor(s1, 8);  s2 += __shfl_xor(s2, 8);
            s1 += __shfl_xor(s1, 16); s2 += __shfl_xor(s2, 16);
            if (lm == 0) {
                const int rowl = rt * 32 + (g & 3) + 8 * (g >> 2) + 4 * half;
                redS[rowl * 8 + wv] = s1;
                redQ[rowl * 8 + wv] = s2;
            }
        }
    }
    __syncthreads();
    if (tid < 64) {
        float S = 0.f, Q = 0.f;
#pragma unroll
        for (int i = 0; i < 8; i++) { S += redS[tid * 8 + i]; Q += redQ[tid * 8 + i]; }
        const float mu = S * (1.f / 768.f);
        const float var = Q * (1.f / 768.f) - mu * mu;
        muA[tid] = mu;
        rsA[tid] = rsqrtf(var + 1e-5f);
    }
    __syncthreads();

    // ---- normalize + store (f32)
#pragma unroll
    for (int rt = 0; rt < 2; ++rt) {
#pragma unroll
        for (int g = 0; g < 16; ++g) {
            const int rowl = rt * 32 + (g & 3) + 8 * (g >> 2) + 4 * half;
            const float mu = muA[rowl], rs = rsA[rowl];
            float* orow = &out[(size_t)(r0 + rowl) * DOUT + wv * 96 + lm];
#pragma unroll
            for (int ct = 0; ct < 3; ++ct) {
                orow[ct * 32] = (acc[rt][ct][g] - mu) * rs * gmv[ct] + btv[ct];
            }
        }
    }
}

// ---------------------------------------------------------------- K2: fix
// Recompute flagged rows exactly: fp64 wi + haar classify, fp32 everything
// else (strictly more accurate than the bf16 main path). ~200 rows expected;
// duplicate rows write identical values (benign race).
__global__ __launch_bounds__(256) void fix_kernel(
    const float* __restrict__ x, const float* __restrict__ W,
    const float* __restrict__ bb, const float* __restrict__ Wp,
    const float* __restrict__ bp, const float* __restrict__ Wc,
    const float* __restrict__ bc, const float* __restrict__ sc,
    const float* __restrict__ tr, const float* __restrict__ gm,
    const float* __restrict__ bt, const unsigned* __restrict__ wl,
    float* __restrict__ out)
{
    __shared__ float  xrow[DIN];
    __shared__ double wpart[NWAV][4];
    __shared__ float  wavS[NWAV];
    __shared__ float  hrow[DOUT];
    __shared__ float  redS2[4], redQ2[4];
    __shared__ float  mu_s, rs_s;

    unsigned cnt = wl[0];
    if (cnt > WL_CAP - 1) cnt = WL_CAP - 1;
    const int tid = threadIdx.x;

    for (unsigned it = blockIdx.x; it < cnt; it += gridDim.x) {
        const int row = (int)wl[1 + it];

        for (int k = tid; k < DIN; k += 256) xrow[k] = x[(size_t)row * DIN + k];
        __syncthreads();

        // wi[j] in fp64 (4 partials per j), then wavelet + GELU
        if (tid < NWAV * 4) {
            const int j = tid >> 2, q = tid & 3;
            const float* wr = &Wp[(size_t)j * DIN + q * 192];
            const float* xr = &xrow[q * 192];
            double a0 = 0.0, a1 = 0.0, a2 = 0.0, a3 = 0.0;
            for (int k = 0; k < 192; k += 4) {
                a0 = fma((double)xr[k + 0], (double)wr[k + 0], a0);
                a1 = fma((double)xr[k + 1], (double)wr[k + 1], a1);
                a2 = fma((double)xr[k + 2], (double)wr[k + 2], a2);
                a3 = fma((double)xr[k + 3], (double)wr[k + 3], a3);
            }
            wpart[j][q] = (a0 + a1) + (a2 + a3);
        }
        __syncthreads();
        if (tid < NWAV) {
            const int j = tid;
            const double wid = ((wpart[j][0] + wpart[j][1]) +
                                (wpart[j][2] + wpart[j][3])) + (double)bp[j];
            const double sd = (wid - (double)tr[j]) / (double)sc[j];
            double w;
            if (j < 16) {
                w = (sd >= 0.0 && sd < 0.5) ? 1.0 : ((sd >= 0.5 && sd < 1.0) ? -1.0 : 0.0);
            } else if (j < 32) {
                w = (1.0 - sd * sd) * exp(-0.5 * sd * sd);
            } else {
                w = cos(5.0 * sd) * exp(-0.5 * sd * sd);
            }
            const double gel = 0.5 * w * (1.0 + erf(w * 0.70710678118654752));
            wavS[j] = (float)gel;
        }
        __syncthreads();

        // h[row, c] for all c (3 cols/thread), fp64 direct accumulate
        for (int c = tid; c < DOUT; c += 256) {
            const float* wr = &W[(size_t)c * DIN];
            double a0 = 0.0, a1 = 0.0, a2 = 0.0, a3 = 0.0;
            for (int k = 0; k < DIN; k += 4) {
                a0 = fma((double)xrow[k + 0], (double)wr[k + 0], a0);
                a1 = fma((double)xrow[k + 1], (double)wr[k + 1], a1);
                a2 = fma((double)xrow[k + 2], (double)wr[k + 2], a2);
                a3 = fma((double)xrow[k + 3], (double)wr[k + 3], a3);
            }
            float wp_ = 0.f;
            const float* wcr = &Wc[(size_t)c * NWAV];
#pragma unroll
            for (int j = 0; j < NWAV; j++) wp_ += wavS[j] * wcr[j];
            hrow[c] = (float)((a0 + a1) + (a2 + a3)) + bb[c] + wp_ + bc[c];
        }
        __syncthreads();

        // LayerNorm over the row
        float S = 0.f, Q = 0.f;
        for (int c = tid; c < DOUT; c += 256) { const float v = hrow[c]; S += v; Q += v * v; }
        S += __shfl_xor(S, 1);  Q += __shfl_xor(Q, 1);
        S += __shfl_xor(S, 2);  Q += __shfl_xor(Q, 2);
        S += __shfl_xor(S, 4);  Q += __shfl_xor(Q, 4);
        S += __shfl_xor(S, 8);  Q += __shfl_xor(Q, 8);
        S += __shfl_xor(S, 16); Q += __shfl_xor(Q, 16);
        S += __shfl_xor(S, 32); Q += __shfl_xor(Q, 32);
        if ((tid & 63) == 0) { redS2[tid >> 6] = S; redQ2[tid >> 6] = Q; }
        __syncthreads();
        if (tid == 0) {
            float Ss = 0.f, Qs = 0.f;
#pragma unroll
            for (int i = 0; i < 4; i++) { Ss += redS2[i]; Qs += redQ2[i]; }
            const float mu = Ss * (1.f / 768.f);
            const float var = Qs * (1.f / 768.f) - mu * mu;
            mu_s = mu;
            rs_s = rsqrtf(var + 1e-5f);
        }
        __syncthreads();
        for (int c = tid; c < DOUT; c += 256)
            out[(size_t)row * DOUT + c] = (hrow[c] - mu_s) * rs_s * gm[c] + bt[c];
        __syncthreads();  // before next iteration reuses shared buffers
    }
}

// ---------------------------------------------------------------- launcher
extern "C" void kernel_launch(void* const* d_in, const int* in_sizes, int n_in,
                              void* d_out, int out_size, void* d_ws, size_t ws_size,
                              hipStream_t stream)
{
    const float* x  = (const float*)d_in[0];
    const float* W  = (const float*)d_in[1];
    const float* b  = (const float*)d_in[2];
    const float* Wp = (const float*)d_in[3];
    const float* bp = (const float*)d_in[4];
    const float* Wc = (const float*)d_in[5];
    const float* bc = (const float*)d_in[6];
    const float* sc = (const float*)d_in[7];
    const float* tr = (const float*)d_in[8];
    const float* gm = (const float*)d_in[9];
    const float* bt = (const float*)d_in[10];
    float* out = (float*)d_out;
    short* ws  = (short*)d_ws;   // ~1.45 MB packed weights + 32 KB worklist
    unsigned* wl = reinterpret_cast<unsigned*>(ws + WL_OFF);

    pack_kernel<<<dim3(330), dim3(256), 0, stream>>>(W, Wp, Wc, ws);
    fused_kernel<<<dim3(B_SZ / 64), dim3(512), 0, stream>>>(
        x, ws, wl, bp, sc, tr, b, bc, gm, bt, out);
    fix_kernel<<<dim3(256), dim3(256), 0, stream>>>(
        x, W, b, Wp, bp, Wc, bc, sc, tr, gm, bt, wl, out);
}

// Round 2
// 357.823 us; speedup vs baseline: 1.0105x; 1.0105x over previous
//
#include <hip/hip_runtime.h>
#include <math.h>

// WaveletKANClassifier, MI355X gfx950. fp32 I/O, bf16 MFMA compute.
//
// Round-5: weight-load latency was the wall (round-4: all pipes <16%, 2
// waves/SIMD because acc regs (112) + arch (88) cap residency; per-wave
// serialized L2/L3-latency B-frag loads + vmcnt(0) drain at every
// __syncthreads). This round:
//  - B-fragments stream via global_load_lds into per-wave private LDS
//    slots (3-slot rotation, 2-group lookahead, counted vmcnt - never 0
//    in the loop). No barrier needed: each wave consumes its own tiles.
//  - K-loop barrier is raw "lgkmcnt(0); s_barrier" so the DMA queue
//    survives iteration boundaries.
//  - lgkmcnt(0) before each group issue guards slot reuse vs in-flight
//    ds_read.
//  - x prefetch made unconditional (clamped addr) so vmcnt counts are
//    exact in every iteration.
//  - fix_kernel: direct path fp32 (wi stays fp64) - cheaper cleanup.

#define B_SZ  32768
#define DIN   768
#define DOUT  768
#define NWAV  48

// d_ws fragment-major layout (units: shorts). Fragment tile = 64 lanes x 8
// bf16 = 512 shorts; lane L holds M[c0+(L&31)][k0 + (L>>5)*8 + j].
#define WF_OFF   0        // W:  24 cb x 48 kb tiles = 589824
#define WPH_OFF  589824   // Wp hi: 2 ct x 48 kb = 49152
#define WPL_OFF  638976   // Wp lo: 49152
#define WCF_OFF  688128   // Wc: 24 cb x 3 kb = 36864
#define WL_OFF   724992   // worklist: u32 count + u32 rows[WL_CAP-1]
#define WL_CAP   8192

typedef short bf16x8 __attribute__((ext_vector_type(8)));
typedef float f32x16 __attribute__((ext_vector_type(16)));

__device__ __forceinline__ float bf2f(short u) {
    union { unsigned int i; float f; } v;
    v.i = ((unsigned int)(unsigned short)u) << 16;
    return v.f;
}
__device__ __forceinline__ short f2bf(float f) {
    union { float f; unsigned int i; } v; v.f = f;
    unsigned int r = v.i + 0x7FFFu + ((v.i >> 16) & 1u);  // RNE
    return (short)(r >> 16);
}

// async global->LDS DMA: 16 B/lane, dst = wave-uniform base + lane*16
__device__ __forceinline__ void dma16(const short* g, char* l) {
    __builtin_amdgcn_global_load_lds(
        (const __attribute__((address_space(1))) void*)g,
        (__attribute__((address_space(3))) void*)l, 16, 0, 0);
}

#define LGKM0()  asm volatile("s_waitcnt lgkmcnt(0)" ::: "memory")
#define VMW(N)   asm volatile("s_waitcnt vmcnt(" #N ")" ::: "memory")
#define BARSYNC() asm volatile("s_waitcnt lgkmcnt(0)\n\ts_barrier" ::: "memory")

// ---------------------------------------------------------------- K0: pack
__global__ __launch_bounds__(256) void pack_kernel(
    const float* __restrict__ W, const float* __restrict__ Wp,
    const float* __restrict__ Wc, short* __restrict__ ws)
{
    if (blockIdx.x == 0 && threadIdx.x == 0)
        *reinterpret_cast<unsigned*>(ws + WL_OFF) = 0u;  // reset worklist

    const int gw = (blockIdx.x * 256 + threadIdx.x) >> 6;
    const int L  = threadIdx.x & 63;
    const int lm = L & 31, half = L >> 5;

    if (gw < 1152) {                       // W [768 x 768]
        const int cb = gw / 48, kb = gw % 48;
        const int row = cb * 32 + lm;
        const int k = kb * 16 + half * 8;
        bf16x8 o;
#pragma unroll
        for (int j = 0; j < 8; j++) o[j] = f2bf(W[(size_t)row * DIN + k + j]);
        *reinterpret_cast<bf16x8*>(&ws[WF_OFF + (size_t)gw * 512 + L * 8]) = o;
    } else if (gw < 1248) {                // Wp [48 x 768], hi/lo, pad rows->64
        const int t = gw - 1152;
        const int ct = t / 48, kb = t % 48;
        const int j = ct * 32 + lm;
        const int k = kb * 16 + half * 8;
        bf16x8 h, l;
#pragma unroll
        for (int jj = 0; jj < 8; jj++) {
            float v = (j < NWAV) ? Wp[(size_t)j * DIN + k + jj] : 0.f;
            const short hh = f2bf(v);
            h[jj] = hh;
            l[jj] = f2bf(v - bf2f(hh));
        }
        *reinterpret_cast<bf16x8*>(&ws[WPH_OFF + (size_t)t * 512 + L * 8]) = h;
        *reinterpret_cast<bf16x8*>(&ws[WPL_OFF + (size_t)t * 512 + L * 8]) = l;
    } else if (gw < 1320) {                // Wc [768 x 48]
        const int t = gw - 1248;
        const int cb = t / 3, kb = t % 3;
        const int row = cb * 32 + lm;
        const int k = kb * 16 + half * 8;
        bf16x8 o;
#pragma unroll
        for (int jj = 0; jj < 8; jj++) o[jj] = f2bf(Wc[(size_t)row * NWAV + k + jj]);
        *reinterpret_cast<bf16x8*>(&ws[WCF_OFF + (size_t)t * 512 + L * 8]) = o;
    }
}

// issue one weight group (kb index m) into slot base sp
__device__ __forceinline__ void issue_group(
    const short* WF, const short* WPH, const short* WPL,
    char* sp, int wv3, int wct48, int m, int L8, bool wi)
{
#pragma unroll
    for (int ct = 0; ct < 3; ++ct)
        dma16(&WF[((size_t)((wv3 + ct) * 48 + m)) * 512 + L8], sp + ct * 1024);
    if (wi) {
        dma16(&WPH[((size_t)(wct48 + m)) * 512 + L8], sp + 3 * 1024);
        dma16(&WPL[((size_t)(wct48 + m)) * 512 + L8], sp + 4 * 1024);
    }
}

// ---------------------------------------------------------------- K1: fused
__global__ __launch_bounds__(512, 2) void fused_kernel(
    const float* __restrict__ x, const short* __restrict__ ws,
    unsigned* __restrict__ wl,
    const float* __restrict__ bp, const float* __restrict__ sc,
    const float* __restrict__ tr,
    const float* __restrict__ bb, const float* __restrict__ bc,
    const float* __restrict__ gm, const float* __restrict__ bt,
    float* __restrict__ out)
{
    // x tiles: 64 rows x 64 k bf16, row stride 72 shorts (9 granules of 16B,
    // coprime 8 -> conflict-free b128 frag reads). Double-buffered hi + lo.
    __shared__ __align__(16) short xh[2][64 * 72];
    __shared__ __align__(16) short xl[2][64 * 72];
    // per-wave private weight slots: waves 0-3: 3 slots x 5 KiB; 4-7: 3 x 3 KiB
    __shared__ __align__(16) char wsl[4 * 15360 + 4 * 9216];   // 98304 B
    __shared__ float redS[64 * 8], redQ[64 * 8];
    __shared__ float muA[64], rsA[64];

    const short* WF  = ws + WF_OFF;
    const short* WPH = ws + WPH_OFF;
    const short* WPL = ws + WPL_OFF;
    const short* WCF = ws + WCF_OFF;

    const int tid = threadIdx.x;
    const int r0  = blockIdx.x * 64;
    const int L = tid & 63;
    const int wv = __builtin_amdgcn_readfirstlane(tid >> 6);   // wave-uniform
    const int lm  = L & 31, half = L >> 5;
    const int L8  = L * 8;
    const bool wi = (wv < 4);
    const int wv3 = wv * 3;
    const int wrt = wv & 1, wct = wv >> 1;     // wi tile for wv<4
    const int wct48 = wct * 48;

    char* myslot = wsl + (wi ? wv * 15360 : 61440 + (wv - 4) * 9216);
    const int SLOTB = wi ? 5120 : 3072;

    f32x16 acc[2][3];                 // [rt (row 32-block)][ct (col 32-block)]
#pragma unroll
    for (int rt = 0; rt < 2; rt++)
#pragma unroll
        for (int ct = 0; ct < 3; ct++)
#pragma unroll
            for (int g = 0; g < 16; g++) acc[rt][ct][g] = 0.f;
    f32x16 wacc;                      // wi acc (waves 0-3)
#pragma unroll
    for (int g = 0; g < 16; g++) wacc[g] = 0.f;

    // staging role: thread -> (row, 8-k chunk)
    const int srow = tid >> 3;
    const int sk   = (tid & 7) * 8;

    // ---- prologue: stage x chunk 0 into buf 0; issue weight groups 0,1
    {
        const float4* xp = reinterpret_cast<const float4*>(&x[(size_t)(r0 + srow) * DIN + sk]);
        const float4 v0 = xp[0], v1 = xp[1];
        const float f[8] = {v0.x, v0.y, v0.z, v0.w, v1.x, v1.y, v1.z, v1.w};
        bf16x8 hh, ll;
#pragma unroll
        for (int i = 0; i < 8; i++) {
            const short h = f2bf(f[i]);
            hh[i] = h;
            ll[i] = f2bf(f[i] - bf2f(h));
        }
        *reinterpret_cast<bf16x8*>(&xh[0][srow * 72 + sk]) = hh;
        *reinterpret_cast<bf16x8*>(&xl[0][srow * 72 + sk]) = ll;
    }
    issue_group(WF, WPH, WPL, myslot,         wv3, wct48, 0, L8, wi);
    issue_group(WF, WPH, WPL, myslot + SLOTB, wv3, wct48, 1, L8, wi);
    BARSYNC();

    // ---- K loop: 12 chunks of 64. Weight group n = 4*k0i+ks, slot n%3.
    // Issue order per step: [issue n+2][wait vmcnt][consume n]. Counted
    // waits (issued-after-n): steps 0,1: {g(n+1), x(2), g(n+2)} = 2G+2;
    // steps 2,3: {g(n+1), g(n+2)} = 2G.  G=5 (waves 0-3), G=3 (waves 4-7).
    int sl = 0;   // k0i % 3
    for (int k0i = 0; k0i < 12; ++k0i) {
        const int cur = k0i & 1;
        // x prefetch (unconditional, clamped: keeps vmcnt arithmetic exact)
        const int nx = (k0i < 11) ? k0i + 1 : 11;
        const float4* xp = reinterpret_cast<const float4*>(
            &x[(size_t)(r0 + srow) * DIN + nx * 64 + sk]);
        const float4 v0 = xp[0], v1 = xp[1];

#pragma unroll
        for (int ks = 0; ks < 4; ++ks) {
            LGKM0();   // prior ds_reads done before DMA may overwrite a slot
            {
                int m = 4 * k0i + ks + 2; if (m >= 48) m -= 48;   // wrap: dummy
                int s = sl + ks + 2; if (s >= 3) s -= 3; if (s >= 3) s -= 3;
                issue_group(WF, WPH, WPL, myslot + s * SLOTB, wv3, wct48, m, L8, wi);
            }
            if (wi) { if (ks < 2) { VMW(12); } else { VMW(10); } }
            else    { if (ks < 2) { VMW(8);  } else { VMW(6);  } }

            int cs = sl + ks; if (cs >= 3) cs -= 3;
            const char* cp = myslot + cs * SLOTB;
            const bf16x8 a0 = *reinterpret_cast<bf16x8*>(&xh[cur][lm * 72 + ks * 16 + half * 8]);
            const bf16x8 a1 = *reinterpret_cast<bf16x8*>(&xh[cur][(32 + lm) * 72 + ks * 16 + half * 8]);
#pragma unroll
            for (int ct = 0; ct < 3; ++ct) {
                const bf16x8 b = *reinterpret_cast<const bf16x8*>(cp + ct * 1024 + L * 16);
                acc[0][ct] = __builtin_amdgcn_mfma_f32_32x32x16_bf16(a0, b, acc[0][ct], 0, 0, 0);
                acc[1][ct] = __builtin_amdgcn_mfma_f32_32x32x16_bf16(a1, b, acc[1][ct], 0, 0, 0);
            }
            if (wi) {
                const bf16x8 ah = wrt ? a1 : a0;
                const bf16x8 al = *reinterpret_cast<bf16x8*>(&xl[cur][(wrt * 32 + lm) * 72 + ks * 16 + half * 8]);
                const bf16x8 bh = *reinterpret_cast<const bf16x8*>(cp + 3 * 1024 + L * 16);
                const bf16x8 bl = *reinterpret_cast<const bf16x8*>(cp + 4 * 1024 + L * 16);
                wacc = __builtin_amdgcn_mfma_f32_32x32x16_bf16(ah, bl, wacc, 0, 0, 0);
                wacc = __builtin_amdgcn_mfma_f32_32x32x16_bf16(al, bh, wacc, 0, 0, 0);
                wacc = __builtin_amdgcn_mfma_f32_32x32x16_bf16(ah, bh, wacc, 0, 0, 0);
            }
        }

        // stage next x chunk into 1-cur (garbage at k0i=11: lands in xh[0]
        // which the wavelet stage overwrites before any read of k<48)
        {
            const float f[8] = {v0.x, v0.y, v0.z, v0.w, v1.x, v1.y, v1.z, v1.w};
            bf16x8 hh, ll;
#pragma unroll
            for (int i = 0; i < 8; i++) {
                const short h = f2bf(f[i]);
                hh[i] = h;
                ll[i] = f2bf(f[i] - bf2f(h));
            }
            *reinterpret_cast<bf16x8*>(&xh[1 - cur][srow * 72 + sk]) = hh;
            *reinterpret_cast<bf16x8*>(&xl[1 - cur][srow * 72 + sk]) = ll;
        }
        BARSYNC();      // raw barrier: DMA queue stays in flight
        sl = (sl == 2) ? 0 : sl + 1;
    }

    // ---- wavelet activation + GELU -> wav tile in LDS (reuse xh[0])
    short* wavL = &xh[0][0];
    if (wi) {
        const int j = wct * 32 + lm;
        if (j < NWAV) {
            const float bpv = bp[j], scv = sc[j], trv = tr[j];
#pragma unroll
            for (int g = 0; g < 16; ++g) {
                const int rowl = wrt * 32 + (g & 3) + 8 * (g >> 2) + 4 * half;  // C/D map
                const float wiv = wacc[g] + bpv;
                const float s = (wiv - trv) / scv;
                float w;
                if (j < 16) {
                    // haar: flag boundary band rows for fix_kernel
                    const float dmin = fminf(fabsf(s), fminf(fabsf(s - 0.5f), fabsf(s - 1.0f)));
                    if (dmin < 2e-4f) {
                        const unsigned idx = atomicAdd(&wl[0], 1u);
                        if (idx < WL_CAP - 1) wl[1 + idx] = (unsigned)(r0 + rowl);
                    }
                    w = (s >= 0.f && s < 0.5f) ? 1.f : ((s >= 0.5f && s < 1.f) ? -1.f : 0.f);
                } else if (j < 32) {
                    w = (1.f - s * s) * expf(-0.5f * s * s);
                } else {
                    w = cosf(5.f * s) * expf(-0.5f * s * s);
                }
                const float gel = 0.5f * w * (1.f + erff(w * 0.70710678118654752f));
                wavL[rowl * 72 + j] = f2bf(gel);
            }
        }
    }
    __syncthreads();

    // ---- h += wav @ Wc^T  (K=48 -> 3 ksteps)
#pragma unroll
    for (int ks = 0; ks < 3; ++ks) {
        const bf16x8 a0 = *reinterpret_cast<bf16x8*>(&wavL[lm * 72 + ks * 16 + half * 8]);
        const bf16x8 a1 = *reinterpret_cast<bf16x8*>(&wavL[(32 + lm) * 72 + ks * 16 + half * 8]);
#pragma unroll
        for (int ct = 0; ct < 3; ++ct) {
            const bf16x8 b = *reinterpret_cast<const bf16x8*>(
                &WCF[((size_t)((wv3 + ct) * 3 + ks)) * 512 + L8]);
            acc[0][ct] = __builtin_amdgcn_mfma_f32_32x32x16_bf16(a0, b, acc[0][ct], 0, 0, 0);
            acc[1][ct] = __builtin_amdgcn_mfma_f32_32x32x16_bf16(a1, b, acc[1][ct], 0, 0, 0);
        }
    }

    // ---- bias + LN reduction
    float bias[3], gmv[3], btv[3];
#pragma unroll
    for (int ct = 0; ct < 3; ++ct) {
        const int col = wv * 96 + ct * 32 + lm;
        bias[ct] = bb[col] + bc[col];
        gmv[ct] = gm[col];
        btv[ct] = bt[col];
    }
#pragma unroll
    for (int rt = 0; rt < 2; ++rt) {
#pragma unroll
        for (int g = 0; g < 16; ++g) {
            const float v0 = acc[rt][0][g] + bias[0];
            const float v1 = acc[rt][1][g] + bias[1];
            const float v2 = acc[rt][2][g] + bias[2];
            acc[rt][0][g] = v0; acc[rt][1][g] = v1; acc[rt][2][g] = v2;
            float s1 = v0 + v1 + v2;
            float s2 = v0 * v0 + v1 * v1 + v2 * v2;
            s1 += __shfl_xor(s1, 1);  s2 += __shfl_xor(s2, 1);
            s1 += __shfl_xor(s1, 2);  s2 += __shfl_xor(s2, 2);
            s1 += __shfl_xor(s1, 4);  s2 += __shfl_xor(s2, 4);
            s1 += __shfl_xor(s1, 8);  s2 += __shfl_xor(s2, 8);
            s1 += __shfl_xor(s1, 16); s2 += __shfl_xor(s2, 16);
            if (lm == 0) {
                const int rowl = rt * 32 + (g & 3) + 8 * (g >> 2) + 4 * half;
                redS[rowl * 8 + wv] = s1;
                redQ[rowl * 8 + wv] = s2;
            }
        }
    }
    __syncthreads();
    if (tid < 64) {
        float S = 0.f, Q = 0.f;
#pragma unroll
        for (int i = 0; i < 8; i++) { S += redS[tid * 8 + i]; Q += redQ[tid * 8 + i]; }
        const float mu = S * (1.f / 768.f);
        const float var = Q * (1.f / 768.f) - mu * mu;
        muA[tid] = mu;
        rsA[tid] = rsqrtf(var + 1e-5f);
    }
    __syncthreads();

    // ---- normalize + store (f32)
#pragma unroll
    for (int rt = 0; rt < 2; ++rt) {
#pragma unroll
        for (int g = 0; g < 16; ++g) {
            const int rowl = rt * 32 + (g & 3) + 8 * (g >> 2) + 4 * half;
            const float mu = muA[rowl], rs = rsA[rowl];
            float* orow = &out[(size_t)(r0 + rowl) * DOUT + wv * 96 + lm];
#pragma unroll
            for (int ct = 0; ct < 3; ++ct) {
                orow[ct * 32] = (acc[rt][ct][g] - mu) * rs * gmv[ct] + btv[ct];
            }
        }
    }
}

// ---------------------------------------------------------------- K2: fix
// Recompute flagged rows: fp64 wi + haar classify, fp32 everything else.
__global__ __launch_bounds__(256) void fix_kernel(
    const float* __restrict__ x, const float* __restrict__ W,
    const float* __restrict__ bb, const float* __restrict__ Wp,
    const float* __restrict__ bp, const float* __restrict__ Wc,
    const float* __restrict__ bc, const float* __restrict__ sc,
    const float* __restrict__ tr, const float* __restrict__ gm,
    const float* __restrict__ bt, const unsigned* __restrict__ wl,
    float* __restrict__ out)
{
    __shared__ float  xrow[DIN];
    __shared__ double wpart[NWAV][4];
    __shared__ float  wavS[NWAV];
    __shared__ float  hrow[DOUT];
    __shared__ float  redS2[4], redQ2[4];
    __shared__ float  mu_s, rs_s;

    unsigned cnt = wl[0];
    if (cnt > WL_CAP - 1) cnt = WL_CAP - 1;
    const int tid = threadIdx.x;

    for (unsigned it = blockIdx.x; it < cnt; it += gridDim.x) {
        const int row = (int)wl[1 + it];

        for (int k = tid; k < DIN; k += 256) xrow[k] = x[(size_t)row * DIN + k];
        __syncthreads();

        if (tid < NWAV * 4) {
            const int j = tid >> 2, q = tid & 3;
            const float* wr = &Wp[(size_t)j * DIN + q * 192];
            const float* xr = &xrow[q * 192];
            double a0 = 0.0, a1 = 0.0, a2 = 0.0, a3 = 0.0;
            for (int k = 0; k < 192; k += 4) {
                a0 = fma((double)xr[k + 0], (double)wr[k + 0], a0);
                a1 = fma((double)xr[k + 1], (double)wr[k + 1], a1);
                a2 = fma((double)xr[k + 2], (double)wr[k + 2], a2);
                a3 = fma((double)xr[k + 3], (double)wr[k + 3], a3);
            }
            wpart[j][q] = (a0 + a1) + (a2 + a3);
        }
        __syncthreads();
        if (tid < NWAV) {
            const int j = tid;
            const double wid = ((wpart[j][0] + wpart[j][1]) +
                                (wpart[j][2] + wpart[j][3])) + (double)bp[j];
            const double sd = (wid - (double)tr[j]) / (double)sc[j];
            double w;
            if (j < 16) {
                w = (sd >= 0.0 && sd < 0.5) ? 1.0 : ((sd >= 0.5 && sd < 1.0) ? -1.0 : 0.0);
            } else if (j < 32) {
                w = (1.0 - sd * sd) * exp(-0.5 * sd * sd);
            } else {
                w = cos(5.0 * sd) * exp(-0.5 * sd * sd);
            }
            const double gel = 0.5 * w * (1.0 + erf(w * 0.70710678118654752));
            wavS[j] = (float)gel;
        }
        __syncthreads();

        // h[row, c] for all c (3 cols/thread), fp32 direct accumulate
        for (int c = tid; c < DOUT; c += 256) {
            const float* wr = &W[(size_t)c * DIN];
            float a0 = 0.f, a1 = 0.f, a2 = 0.f, a3 = 0.f;
            for (int k = 0; k < DIN; k += 4) {
                a0 = fmaf(xrow[k + 0], wr[k + 0], a0);
                a1 = fmaf(xrow[k + 1], wr[k + 1], a1);
                a2 = fmaf(xrow[k + 2], wr[k + 2], a2);
                a3 = fmaf(xrow[k + 3], wr[k + 3], a3);
            }
            float wp_ = 0.f;
            const float* wcr = &Wc[(size_t)c * NWAV];
#pragma unroll
            for (int j = 0; j < NWAV; j++) wp_ += wavS[j] * wcr[j];
            hrow[c] = ((a0 + a1) + (a2 + a3)) + bb[c] + wp_ + bc[c];
        }
        __syncthreads();

        float S = 0.f, Q = 0.f;
        for (int c = tid; c < DOUT; c += 256) { const float v = hrow[c]; S += v; Q += v * v; }
        S += __shfl_xor(S, 1);  Q += __shfl_xor(Q, 1);
        S += __shfl_xor(S, 2);  Q += __shfl_xor(Q, 2);
        S += __shfl_xor(S, 4);  Q += __shfl_xor(Q, 4);
        S += __shfl_xor(S, 8);  Q += __shfl_xor(Q, 8);
        S += __shfl_xor(S, 16); Q += __shfl_xor(Q, 16);
        S += __shfl_xor(S, 32); Q += __shfl_xor(Q, 32);
        if ((tid & 63) == 0) { redS2[tid >> 6] = S; redQ2[tid >> 6] = Q; }
        __syncthreads();
        if (tid == 0) {
            float Ss = 0.f, Qs = 0.f;
#pragma unroll
            for (int i = 0; i < 4; i++) { Ss += redS2[i]; Qs += redQ2[i]; }
            const float mu = Ss * (1.f / 768.f);
            const float var = Qs * (1.f / 768.f) - mu * mu;
            mu_s = mu;
            rs_s = rsqrtf(var + 1e-5f);
        }
        __syncthreads();
        for (int c = tid; c < DOUT; c += 256)
            out[(size_t)row * DOUT + c] = (hrow[c] - mu_s) * rs_s * gm[c] + bt[c];
        __syncthreads();
    }
}

// ---------------------------------------------------------------- launcher
extern "C" void kernel_launch(void* const* d_in, const int* in_sizes, int n_in,
                              void* d_out, int out_size, void* d_ws, size_t ws_size,
                              hipStream_t stream)
{
    const float* x  = (const float*)d_in[0];
    const float* W  = (const float*)d_in[1];
    const float* b  = (const float*)d_in[2];
    const float* Wp = (const float*)d_in[3];
    const float* bp = (const float*)d_in[4];
    const float* Wc = (const float*)d_in[5];
    const float* bc = (const float*)d_in[6];
    const float* sc = (const float*)d_in[7];
    const float* tr = (const float*)d_in[8];
    const float* gm = (const float*)d_in[9];
    const float* bt = (const float*)d_in[10];
    float* out = (float*)d_out;
    short* ws  = (short*)d_ws;
    unsigned* wl = reinterpret_cast<unsigned*>(ws + WL_OFF);

    pack_kernel<<<dim3(330), dim3(256), 0, stream>>>(W, Wp, Wc, ws);
    fused_kernel<<<dim3(B_SZ / 64), dim3(512), 0, stream>>>(
        x, ws, wl, bp, sc, tr, b, bc, gm, bt, out);
    fix_kernel<<<dim3(256), dim3(256), 0, stream>>>(
        x, W, b, Wp, bp, Wc, bc, sc, tr, gm, bt, wl, out);
}